// Round 8
// baseline (927.057 us; speedup 1.0000x reference)
//
#include <hip/hip_runtime.h>
#include <cmath>

#define NN   1000
#define TT   4
#define PP   10
#define DD   13
#define FF   128
#define HH   128
#define EAA  16
#define KDIM 64
#define EE   20000
#define I_NODE 91
#define I_EDGE 169
#define MROW  13000            // N*D
#define OUT_FLOAT4 42250000L   // 13000*13000/4

// zero-M partitions (float4 indices), hidden under D2/D3/D4 role blocks
#define P1_HI 6400000L         // 1250 blocks * 256 * 20
#define P2_HI 12800000L        // + 1250 blocks * 256 * 20
// P3 = [P2_HI, OUT_FLOAT4), 5750 blocks grid-stride

// ---- workspace layout (floats) --------------------------------------------
#define WS_M     0L            // m_buf [N*F]
#define WS_AGG   128000L       // agg   [N*F]
#define WS_NH    256000L       // nh    [N*F]
#define WS_V1    384000L       // V1    [N*H]
#define WS_V2    512000L       // V2    [N*H]
#define WS_U     640000L       // U     [N*128]
#define WS_HMSG  768000L       // hmsg  [E*K]
#define WS_WCOMB 2048000L      // Wcomb [P*K*169]
#define WS_WNC   2156160L      // Wnc   [T*F*169]  (end ~9.0 MB)

// ---- D1 "front": combs + node_msg + agg-zero ------------------------------
#define NB_CE   640
#define NB_CN   512
#define NB_MSG  1000
#define NB_FRONT (NB_CE + NB_CN + NB_MSG)

__global__ __launch_bounds__(256) void k_front(
    const float* __restrict__ We, const float* __restrict__ cobE,
    const float* __restrict__ Wn, const float* __restrict__ cobN,
    const float* __restrict__ nf, const float* __restrict__ Wmsg,
    float* __restrict__ Wcomb, float* __restrict__ Wnc,
    float* __restrict__ m, float* __restrict__ agg) {
  int b = blockIdx.x, t = threadIdx.x;
  if (b < NB_CE) {                       // comb_edge
    if (t < I_EDGE) {
      int pk = b, p = pk >> 6;
      float acc = 0.f;
      const float* wrow = We + pk * I_EDGE;
      const float* crow = cobE + p * I_EDGE * I_EDGE + t;
      for (int i = 0; i < I_EDGE; ++i) acc += wrow[i] * crow[i * I_EDGE];
      Wcomb[pk * I_EDGE + t] = acc;
    }
  } else if (b < NB_CE + NB_CN) {        // comb_node
    if (t < I_EDGE) {
      int tf = b - NB_CE, ty = tf >> 7;
      float acc = 0.f;
      const float* wrow = Wn + tf * I_NODE;
      const float* crow = cobN + ty * I_NODE * I_EDGE + t;
      for (int i = 0; i < I_NODE; ++i) acc += wrow[i] * crow[i * I_EDGE];
      Wnc[tf * I_EDGE + t] = acc;
    }
  } else {                               // node_msg + agg zero
    int n = b - (NB_CE + NB_CN);
    __shared__ float row[FF];
    if (t < FF) row[t] = nf[n * FF + t];
    __syncthreads();
    if (t < FF) {
      float acc = 0.f;
#pragma unroll 8
      for (int f = 0; f < FF; ++f) acc += row[f] * Wmsg[f * FF + t];
      m[n * FF + t] = acc;
    } else {
      agg[n * FF + (t - FF)] = 0.f;
    }
  }
}

// ---- D2: agg atomic scatter ∥ zero P1, round-robin interleaved ------------
// pattern of 9 blocks: 8 scatter + 1 zero -> both roles co-resident, so the
// L2-atomic scatter truly overlaps the HBM-store zero (lesson from R7: a
// contiguous role split serializes because blocks launch in blockIdx order).
#define NB_D2 11250            // 1250 groups x (8 scatter + 1 zero)
__global__ __launch_bounds__(256) void k_scatter_z(
    const float* __restrict__ m, const int* __restrict__ src,
    const int* __restrict__ dst, float* __restrict__ agg,
    float4* __restrict__ Mz) {
  int b = blockIdx.x, t = threadIdx.x;
  int q = b / 9, g = b - q * 9;
  if (g < 8) {                           // scatter (10000 blocks)
    int idx = (q * 8 + g) * 256 + t;
    int e = idx >> 7, j = idx & 127;
    int s = src[e], d = dst[e];
    atomicAdd(&agg[d * FF + j], m[s * FF + j]);
    atomicAdd(&agg[s * FF + j], m[d * FF + j]);
  } else {                               // zero P1 (1250 blocks x 20 f4)
    const float4 z = make_float4(0.f, 0.f, 0.f, 0.f);
    for (long i = (long)q * 256 + t; i < P1_HI; i += 320000L) Mz[i] = z;
  }
}

// ---- D3: node_h + V1/V2/U + nh store ∥ zero P2 ----------------------------
#define NB_D3 2250             // 250 groups x (4 nodes + 5 zero)
__global__ __launch_bounds__(256) void k_nodes_z(
    const float* __restrict__ nf, const float* __restrict__ agg,
    const float* __restrict__ na, const float* __restrict__ Wattr,
    const float* __restrict__ Wem, const float* __restrict__ Wproj,
    float* __restrict__ nh, float* __restrict__ V1, float* __restrict__ V2,
    float* __restrict__ U, float4* __restrict__ Mz) {
  int b = blockIdx.x, t = threadIdx.x;
  int q = b / 9, g = b - q * 9;
  __shared__ float row[FF];
  if (g < 4) {                           // node role (1000 blocks)
    int n = q * 4 + g;
    if (t < FF) {
      float a = 0.f;
#pragma unroll
      for (int p = 0; p < TT; ++p) a += na[n * TT + p] * Wattr[p * FF + t];
      float v = nf[n * FF + t] + agg[n * FF + t] * (1.0f / 20.0f) + a;
      row[t] = v;
      nh[n * FF + t] = v;
    }
    __syncthreads();
    if (t < FF) {
      float v1 = 0.f, v2 = 0.f;
#pragma unroll 4
      for (int f = 0; f < FF; ++f) {
        float x = row[f];
        v1 += x * Wem[f * HH + t];
        v2 += x * Wem[(FF + f) * HH + t];
      }
      V1[n * HH + t] = v1;
      V2[n * HH + t] = v2;
      int k = t & 63, half = t >> 6;
      const float* W = Wproj + (FF + half * FF) * KDIM + k;
      float u = 0.f;
#pragma unroll 4
      for (int f = 0; f < FF; ++f) u += row[f] * W[f * KDIM];
      U[n * 128 + t] = u;
    }
  } else {                               // zero P2 (1250 blocks x 20 f4)
    int zid = q * 5 + (g - 4);
    const float4 z = make_float4(0.f, 0.f, 0.f, 0.f);
    for (long i = P1_HI + (long)zid * 256 + t; i < P2_HI; i += 320000L) Mz[i] = z;
  }
}

// ---- D4: edge message+projection ∥ zero P3 --------------------------------
#define EPB 8
#define NB_D4 8250             // 500x(5 msg + 11 zero) + 250 zero tail
__global__ __launch_bounds__(256) void k_edge_msg_z(
    const float* __restrict__ V1, const float* __restrict__ V2,
    const float* __restrict__ ef, const float* __restrict__ ea,
    const int* __restrict__ src, const int* __restrict__ dst,
    const float* __restrict__ Wem, const float* __restrict__ Wproj,
    float* __restrict__ hmsg, float4* __restrict__ Mz) {
  int b = blockIdx.x, t = threadIdx.x;
  int zid = -1, mi = -1;
  if (b < 8000) {
    int q = b >> 4, g = b & 15;
    if (g < 5) mi = q * 5 + g;           // 2500 msg blocks
    else       zid = q * 11 + (g - 5);   // 5500 zero blocks
  } else {
    zid = 5500 + (b - 8000);             // 250 more zero blocks (=5750)
  }
  if (zid >= 0) {                        // zero P3: [P2_HI, OUT_FLOAT4)
    const float4 z = make_float4(0.f, 0.f, 0.f, 0.f);
    for (long i = P2_HI + (long)zid * 256 + t; i < OUT_FLOAT4; i += 1472000L)
      Mz[i] = z;
    return;
  }
  // ---- msg role: identical to the proven R2 kernel (128 active threads) ---
  int e0 = mi * EPB;
  int j = t;                             // only t<128 participates in work
  __shared__ float efa[EPB][32];
  __shared__ float em[EPB][HH];
  if (j < 128) {
    for (int i = j; i < EPB * 32; i += 128) {
      int e = i >> 5, c = i & 31;
      efa[e][c] = (c < 16) ? ef[(e0 + e) * EAA + c] : ea[(e0 + e) * EAA + (c - 16)];
    }
  }
  __syncthreads();
  if (j < 128) {
    float wcol[32];
#pragma unroll
    for (int c = 0; c < 32; ++c) wcol[c] = Wem[(256 + c) * HH + j];
#pragma unroll
    for (int e = 0; e < EPB; ++e) {
      int s = src[e0 + e], d = dst[e0 + e];
      float acc = V1[s * HH + j] + V2[d * HH + j];
#pragma unroll
      for (int c = 0; c < 32; ++c) acc += efa[e][c] * wcol[c];
      em[e][j] = tanhf(acc);
    }
  }
  __syncthreads();
  if (j < 128) {
    int k = j & 63, half = j >> 6;
    float a0 = 0.f, a1 = 0.f, a2 = 0.f, a3 = 0.f;
    for (int f = 0; f < HH; f += 4) {
      float4 m0 = *(const float4*)&em[half + 0][f];
      float4 m1 = *(const float4*)&em[half + 2][f];
      float4 m2 = *(const float4*)&em[half + 4][f];
      float4 m3 = *(const float4*)&em[half + 6][f];
      float w0 = Wproj[(f + 0) * KDIM + k], w1 = Wproj[(f + 1) * KDIM + k];
      float w2 = Wproj[(f + 2) * KDIM + k], w3 = Wproj[(f + 3) * KDIM + k];
      a0 += m0.x * w0 + m0.y * w1 + m0.z * w2 + m0.w * w3;
      a1 += m1.x * w0 + m1.y * w1 + m1.z * w2 + m1.w * w3;
      a2 += m2.x * w0 + m2.y * w1 + m2.z * w2 + m2.w * w3;
      a3 += m3.x * w0 + m3.y * w1 + m3.z * w2 + m3.w * w3;
    }
    hmsg[(e0 + half + 0) * KDIM + k] = a0;
    hmsg[(e0 + half + 2) * KDIM + k] = a1;
    hmsg[(e0 + half + 4) * KDIM + k] = a2;
    hmsg[(e0 + half + 6) * KDIM + k] = a3;
  }
}

// ---- D5 "tail": edge blocks (5000 blocks) + diagonal blocks (1000) --------
// M fully zeroed after D4 -> all M atomics live here.
#define EB2 4
__global__ __launch_bounds__(768) void k_tail(
    const float* __restrict__ U, const float* __restrict__ hmsg,
    const int* __restrict__ src, const int* __restrict__ dst,
    const int* __restrict__ etype, const float* __restrict__ Wcomb,
    const float* __restrict__ nh, const int* __restrict__ ntype,
    const float* __restrict__ Wnc, float* __restrict__ M) {
  int b = blockIdx.x, tf = threadIdx.x;
  __shared__ __align__(16) float h[EB2][2][KDIM];
  __shared__ __align__(16) float tji[EB2][I_EDGE];
  __shared__ float row[FF];
  if (b < 5000) {                        // ---- edge-block role (R2-proven)
    int t = tf % 192, ei = tf / 192;
    int e = b * EB2 + ei;
    int s = src[e], d = dst[e], p = etype[e];
    if (t < 128) {
      int k = t & 63, w = t >> 6;        // w=0 -> ij, w=1 -> ji
      int a = w ? d : s, bb = w ? s : d;
      h[ei][w][k] = hmsg[e * KDIM + k] + U[a * 128 + k] + U[bb * 128 + 64 + k];
    }
    __syncthreads();
    float bij = 0.f, bji = 0.f;
    if (t < I_EDGE) {
      const float* W = Wcomb + p * KDIM * I_EDGE + t;
      for (int k = 0; k < KDIM; k += 4) {
        float4 hi = *(const float4*)&h[ei][0][k];
        float4 hj = *(const float4*)&h[ei][1][k];
        float w0 = W[(k + 0) * I_EDGE], w1 = W[(k + 1) * I_EDGE];
        float w2 = W[(k + 2) * I_EDGE], w3 = W[(k + 3) * I_EDGE];
        bij += hi.x * w0 + hi.y * w1 + hi.z * w2 + hi.w * w3;
        bji += hj.x * w0 + hj.y * w1 + hj.z * w2 + hj.w * w3;
      }
      tji[ei][t] = bji;
    }
    __syncthreads();
    if (t < I_EDGE) {
      int x = t / DD, y = t % DD;
      float eb = 0.5f * (bij + tji[ei][y * DD + x]);
      atomicAdd(&M[(size_t)(s * DD + x) * MROW + (d * DD + y)], eb);
      atomicAdd(&M[(size_t)(d * DD + y) * MROW + (s * DD + x)], eb);
    }
  } else {                               // ---- diagonal-block role
    int n = b - 5000;
    int ty = ntype[n];
    if (tf < FF) row[tf] = nh[n * FF + tf];
    __syncthreads();
    if (tf < I_EDGE) {
      float acc = 0.f;
      const float* W = Wnc + ty * FF * I_EDGE + tf;
#pragma unroll 4
      for (int f = 0; f < FF; ++f) acc += row[f] * W[f * I_EDGE];
      int x = tf / DD, y = tf % DD;
      atomicAdd(&M[(size_t)(n * DD + x) * MROW + (n * DD + y)], acc);
    }
  }
}

extern "C" void kernel_launch(void* const* d_in, const int* in_sizes, int n_in,
                              void* d_out, int out_size, void* d_ws, size_t ws_size,
                              hipStream_t stream) {
  const float* node_feats = (const float*)d_in[0];
  const float* node_attrs = (const float*)d_in[1];
  const float* edge_feats = (const float*)d_in[2];
  const float* edge_attrs = (const float*)d_in[3];
  const int*   edge_index = (const int*)d_in[4];
  const int*   node_types = (const int*)d_in[5];
  const int*   edge_types = (const int*)d_in[6];
  const float* W_msg  = (const float*)d_in[7];
  const float* W_attr = (const float*)d_in[8];
  const float* W_em   = (const float*)d_in[9];
  const float* W_proj = (const float*)d_in[10];
  const float* W_node = (const float*)d_in[11];
  const float* W_edge = (const float*)d_in[12];
  const float* cob_node = (const float*)d_in[13];
  const float* cob_edge = (const float*)d_in[14];

  float* M  = (float*)d_out;
  float* ws = (float*)d_ws;
  float* m_buf = ws + WS_M;
  float* agg   = ws + WS_AGG;
  float* nh    = ws + WS_NH;
  float* V1    = ws + WS_V1;
  float* V2    = ws + WS_V2;
  float* U     = ws + WS_U;
  float* hmsg  = ws + WS_HMSG;
  float* Wcomb = ws + WS_WCOMB;
  float* Wnc   = ws + WS_WNC;

  const int* src = edge_index;        // edge_index[0]
  const int* dst = edge_index + EE;   // edge_index[1]

  k_front     <<<NB_FRONT, 256, 0, stream>>>(W_edge, cob_edge, W_node, cob_node,
                                             node_feats, W_msg, Wcomb, Wnc,
                                             m_buf, agg);
  k_scatter_z <<<NB_D2, 256, 0, stream>>>(m_buf, src, dst, agg, (float4*)M);
  k_nodes_z   <<<NB_D3, 256, 0, stream>>>(node_feats, agg, node_attrs, W_attr,
                                          W_em, W_proj, nh, V1, V2, U, (float4*)M);
  k_edge_msg_z<<<NB_D4, 256, 0, stream>>>(V1, V2, edge_feats, edge_attrs, src, dst,
                                          W_em, W_proj, hmsg, (float4*)M);
  k_tail      <<<6000, 768, 0, stream>>>(U, hmsg, src, dst, edge_types, Wcomb,
                                         nh, node_types, Wnc, M);
}